// Round 2
// baseline (9354.181 us; speedup 1.0000x reference)
//
#include <hip/hip_runtime.h>

// Decoder LSTM: B=32, T=511 steps, H=1024, 4H=4096, V=32000
// out = res[32][511][1024] ++ hT[32][1024] ++ cT[32][1024]  (fp32)

typedef __bf16 bf16;
typedef __bf16 bf16x4 __attribute__((ext_vector_type(4)));
typedef __bf16 bf16x8 __attribute__((ext_vector_type(8)));
typedef float f32x4 __attribute__((ext_vector_type(4)));

#define M_TOT 16352        // 511*32 rows of x_proj
#define RES_STRIDE 523264  // 511*1024
#define HT_OFF 16744448    // 32*511*1024
#define CT_OFF 16777216    // HT_OFF + 32768

// ---------- fp32 -> bf16 conversion (n4 = n/4 groups) ----------
__global__ void cvt_kernel(const float* __restrict__ src, bf16* __restrict__ dst, int n4) {
    int i = blockIdx.x * blockDim.x + threadIdx.x;
    if (i < n4) {
        float4 v = ((const float4*)src)[i];
        bf16x4 o;
        o[0] = (bf16)v.x; o[1] = (bf16)v.y; o[2] = (bf16)v.z; o[3] = (bf16)v.w;
        ((bf16x4*)dst)[i] = o;
    }
}

// ---------- init h0 (bf16) ----------
__global__ void init_state(const float* __restrict__ h0, bf16* __restrict__ hbuf) {
    int i = blockIdx.x * blockDim.x + threadIdx.x;
    if (i < 32768) hbuf[i] = (bf16)h0[i];
}

// ---------- x_proj GEMM: P[m][j] = emb[tok(m)] . W_ih[j] + bias[j], bf16 out ----------
__global__ __launch_bounds__(256) void gemm_xproj(
    const int* __restrict__ tgt, const bf16* __restrict__ emb,
    const bf16* __restrict__ wih, const float* __restrict__ bih,
    const float* __restrict__ bhh, bf16* __restrict__ P)
{
    __shared__ bf16 As[128 * 72];
    __shared__ bf16 Bs[128 * 72];
    __shared__ int tok[128];

    const int tid  = threadIdx.x;
    const int lane = tid & 63;
    const int wave = tid >> 6;
    const int wm = wave & 1, wn = wave >> 1;
    const int tileM = blockIdx.y * 128;
    const int tileN = blockIdx.x * 128;

    if (tid < 128) {
        int m = tileM + tid;
        int token = 0;
        if (m < M_TOT) {
            int t = m >> 5, b = m & 31;
            token = tgt[b * 512 + t];
            if ((unsigned)token >= 32000u) token = 0;
        }
        tok[tid] = token;
    }
    __syncthreads();

    f32x4 acc[4][4] = {};

    for (int k0 = 0; k0 < 1024; k0 += 64) {
        #pragma unroll
        for (int i = 0; i < 4; ++i) {
            int chunk = i * 256 + tid;
            int row = chunk >> 3;
            int kc  = (chunk & 7) * 8;
            const bf16* srcA = emb + (long)tok[row] * 1024 + k0 + kc;
            *(uint4*)&As[row * 72 + kc] = *(const uint4*)srcA;
            const bf16* srcB = wih + (long)(tileN + row) * 1024 + k0 + kc;
            *(uint4*)&Bs[row * 72 + kc] = *(const uint4*)srcB;
        }
        __syncthreads();
        #pragma unroll
        for (int kk = 0; kk < 64; kk += 32) {
            bf16x8 a[4], b[4];
            #pragma unroll
            for (int f = 0; f < 4; ++f) {
                a[f] = *(const bf16x8*)&As[(wm * 64 + f * 16 + (lane & 15)) * 72 + kk + (lane >> 4) * 8];
                b[f] = *(const bf16x8*)&Bs[(wn * 64 + f * 16 + (lane & 15)) * 72 + kk + (lane >> 4) * 8];
            }
            #pragma unroll
            for (int mf = 0; mf < 4; ++mf)
                #pragma unroll
                for (int nf = 0; nf < 4; ++nf)
                    acc[mf][nf] = __builtin_amdgcn_mfma_f32_16x16x32_bf16(a[mf], b[nf], acc[mf][nf], 0, 0, 0);
        }
        __syncthreads();
    }

    float bias[4];
    #pragma unroll
    for (int nf = 0; nf < 4; ++nf) {
        int j = tileN + wn * 64 + nf * 16 + (lane & 15);
        bias[nf] = bih[j] + bhh[j];
    }
    #pragma unroll
    for (int mf = 0; mf < 4; ++mf) {
        int mBase = tileM + wm * 64 + mf * 16 + ((lane >> 4) * 4);
        #pragma unroll
        for (int r = 0; r < 4; ++r) {
            int m = mBase + r;
            if (m < M_TOT) {
                #pragma unroll
                for (int nf = 0; nf < 4; ++nf) {
                    int j = tileN + wn * 64 + nf * 16 + (lane & 15);
                    P[(long)m * 4096 + j] = (bf16)(acc[mf][nf][r] + bias[nf]);
                }
            }
        }
    }
}

// ---------- persistent LSTM: 64 blocks x 16 h-cols, all 511 steps, grid barrier ----------
__global__ __launch_bounds__(256, 1) void lstm_persist(
    const bf16* __restrict__ P, const bf16* __restrict__ whh,
    const bf16* __restrict__ h0b, const float* __restrict__ c0,
    float* __restrict__ out, bf16* __restrict__ hB0, bf16* __restrict__ hB1,
    unsigned int* __restrict__ cnt)
{
    __shared__ bf16 hs[32 * 1024];   // h staged (XOR-swizzled); aliased as gate-exchange fp32

    const int tid  = threadIdx.x;
    const int lane = tid & 63;
    const int wave = tid >> 6;            // = gate index (i,f,g,o)
    const int c0col = blockIdx.x * 16;    // h-column base

    const int n  = lane & 15;             // MFMA col within tile
    const int kg = lane >> 4;             // k-group 0..3

    // ---- preload this wave's W_hh rows into 128 VGPRs (reused for 511 steps) ----
    bf16x8 wreg[32];
    {
        const bf16* wrow = whh + ((long)(wave * 1024 + c0col + n)) * 1024 + kg * 8;
        #pragma unroll
        for (int i = 0; i < 32; ++i) wreg[i] = *(const bf16x8*)(wrow + i * 32);
    }

    // ---- c state in registers (block owns its cols; fixed thread->(b,col) map) ----
    const int eb   = tid >> 4;            // 0..15
    const int ecol = tid & 15;
    const int hcol = c0col + ecol;
    float cReg0 = c0[eb * 1024 + hcol];
    float cReg1 = c0[(eb + 16) * 1024 + hcol];

    const int m0 = n, m1 = n + 16;

    for (int t = 0; t < 511; ++t) {
        const bf16* hin  = (t == 0) ? h0b : ((t & 1) ? hB0 : hB1);
        bf16*       hout = (t & 1) ? hB1 : hB0;

        // stage h -> LDS (XOR swizzle on 16B chunks)
        #pragma unroll
        for (int i = 0; i < 16; ++i) {
            int chunk = i * 256 + tid;
            int row = chunk >> 7;
            int cIn = chunk & 127;
            *(uint4*)&hs[row * 1024 + ((cIn ^ (row & 7)) << 3)] =
                *(const uint4*)&hin[row * 1024 + (cIn << 3)];
        }
        __syncthreads();

        // prefetch P[t] for this thread's epilogue (HBM latency hides under K-loop)
        long pb  = (long)t * 131072 + eb * 4096 + hcol;
        long pb2 = pb + 16 * 4096;
        float p0 = (float)P[pb],        p1 = (float)P[pb + 1024];
        float p2 = (float)P[pb + 2048], p3 = (float)P[pb + 3072];
        float q0 = (float)P[pb2],        q1 = (float)P[pb2 + 1024];
        float q2 = (float)P[pb2 + 2048], q3 = (float)P[pb2 + 3072];

        f32x4 accA = {0.f, 0.f, 0.f, 0.f};
        f32x4 accB = {0.f, 0.f, 0.f, 0.f};
        #pragma unroll
        for (int i = 0; i < 32; ++i) {
            int ch = i * 4 + kg;          // 16B-chunk index of this frag's k
            bf16x8 a0 = *(const bf16x8*)&hs[m0 * 1024 + ((ch ^ (m0 & 7)) << 3)];
            bf16x8 a1 = *(const bf16x8*)&hs[m1 * 1024 + ((ch ^ (m1 & 7)) << 3)];
            accA = __builtin_amdgcn_mfma_f32_16x16x32_bf16(a0, wreg[i], accA, 0, 0, 0);
            accB = __builtin_amdgcn_mfma_f32_16x16x32_bf16(a1, wreg[i], accB, 0, 0, 0);
        }

        __syncthreads();                  // hs reads done; alias as gate exchange
        float* gs = (float*)hs;           // gs[(gate*32+row)*16 + col]
        #pragma unroll
        for (int r = 0; r < 4; ++r) {
            int row = (lane >> 4) * 4 + r;    // C/D: row=(lane>>4)*4+reg, col=lane&15
            gs[(wave * 32 + row) * 16 + n]      = accA[r];
            gs[(wave * 32 + row + 16) * 16 + n] = accB[r];
        }
        __syncthreads();

        // epilogue: this thread owns (eb,hcol) and (eb+16,hcol)
        {
            float gi = gs[(0 * 32 + eb) * 16 + ecol] + p0;
            float gf = gs[(1 * 32 + eb) * 16 + ecol] + p1;
            float gg = gs[(2 * 32 + eb) * 16 + ecol] + p2;
            float go = gs[(3 * 32 + eb) * 16 + ecol] + p3;
            float ig = 1.f / (1.f + __expf(-gi));
            float fg = 1.f / (1.f + __expf(-gf));
            float g  = tanhf(gg);
            float og = 1.f / (1.f + __expf(-go));
            cReg0 = fg * cReg0 + ig * g;
            float hnew = og * tanhf(cReg0);
            hout[eb * 1024 + hcol] = (bf16)hnew;
            out[(long)eb * RES_STRIDE + (long)t * 1024 + hcol] = hnew;
            if (t == 510) {
                out[HT_OFF + eb * 1024 + hcol] = hnew;
                out[CT_OFF + eb * 1024 + hcol] = cReg0;
            }
        }
        {
            float gi = gs[(0 * 32 + eb + 16) * 16 + ecol] + q0;
            float gf = gs[(1 * 32 + eb + 16) * 16 + ecol] + q1;
            float gg = gs[(2 * 32 + eb + 16) * 16 + ecol] + q2;
            float go = gs[(3 * 32 + eb + 16) * 16 + ecol] + q3;
            float ig = 1.f / (1.f + __expf(-gi));
            float fg = 1.f / (1.f + __expf(-gf));
            float g  = tanhf(gg);
            float og = 1.f / (1.f + __expf(-go));
            cReg1 = fg * cReg1 + ig * g;
            float hnew = og * tanhf(cReg1);
            hout[(eb + 16) * 1024 + hcol] = (bf16)hnew;
            out[(long)(eb + 16) * RES_STRIDE + (long)t * 1024 + hcol] = hnew;
            if (t == 510) {
                out[HT_OFF + (eb + 16) * 1024 + hcol] = hnew;
                out[CT_OFF + (eb + 16) * 1024 + hcol] = cReg1;
            }
        }

        // grid barrier (monotonic counter; 64 blocks all co-resident)
        if (t < 510) {
            __threadfence();
            __syncthreads();
            if (tid == 0) {
                __hip_atomic_fetch_add(cnt, 1u, __ATOMIC_ACQ_REL, __HIP_MEMORY_SCOPE_AGENT);
                unsigned int target = 64u * (unsigned)(t + 1);
                while (__hip_atomic_load(cnt, __ATOMIC_ACQUIRE, __HIP_MEMORY_SCOPE_AGENT) < target)
                    __builtin_amdgcn_s_sleep(1);
            }
            __syncthreads();
            __threadfence();
        }
    }
}

extern "C" void kernel_launch(void* const* d_in, const int* in_sizes, int n_in,
                              void* d_out, int out_size, void* d_ws, size_t ws_size,
                              hipStream_t stream) {
    const int*   tgt  = (const int*)d_in[0];
    const float* h0   = (const float*)d_in[1];
    const float* c0   = (const float*)d_in[2];
    const float* embT = (const float*)d_in[5];
    const float* wih  = (const float*)d_in[6];
    const float* whh  = (const float*)d_in[7];
    const float* bih  = (const float*)d_in[8];
    const float* bhh  = (const float*)d_in[9];
    float* out = (float*)d_out;

    char* ws = (char*)d_ws;
    bf16*  P    = (bf16*)(ws);                 // 133,955,584 B
    bf16*  embB = (bf16*)(ws + 133955584);     // 65,536,000 B
    bf16*  wihB = (bf16*)(ws + 199491584);     //  8,388,608 B
    bf16*  whhB = (bf16*)(ws + 207880192);     //  8,388,608 B
    bf16*  hA   = (bf16*)(ws + 216268800);     // 65,536 B
    bf16*  hB0  = (bf16*)(ws + 216334336);     // 65,536 B
    bf16*  hB1  = (bf16*)(ws + 216399872);     // 65,536 B
    unsigned int* cnt = (unsigned int*)(ws + 216465408);  // barrier counter

    hipMemsetAsync(cnt, 0, 128, stream);

    cvt_kernel<<<32000, 256, 0, stream>>>(embT, embB, 32768000 / 4);
    cvt_kernel<<<4096, 256, 0, stream>>>(wih, wihB, 4194304 / 4);
    cvt_kernel<<<4096, 256, 0, stream>>>(whh, whhB, 4194304 / 4);
    init_state<<<128, 256, 0, stream>>>(h0, hA);

    dim3 g(32, 128);
    gemm_xproj<<<g, 256, 0, stream>>>(tgt, embB, wihB, bih, bhh, P);

    lstm_persist<<<64, 256, 0, stream>>>(P, whhB, hA, c0, out, hB0, hB1, cnt);
}

// Round 3
// 3553.311 us; speedup vs baseline: 2.6325x; 2.6325x over previous
//
#include <hip/hip_runtime.h>

// Decoder LSTM: B=32, T=511 steps, H=1024, 4H=4096, V=32000
// out = res[32][511][1024] ++ hT[32][1024] ++ cT[32][1024]  (fp32)

typedef __bf16 bf16;
typedef __bf16 bf16x4 __attribute__((ext_vector_type(4)));
typedef __bf16 bf16x8 __attribute__((ext_vector_type(8)));
typedef float f32x4 __attribute__((ext_vector_type(4)));

#define M_TOT 16352        // 511*32 rows of x_proj
#define RES_STRIDE 523264  // 511*1024
#define HT_OFF 16744448    // 32*511*1024
#define CT_OFF 16777216    // HT_OFF + 32768

// Coherent (cross-XCD) 16B load: sc1 bypasses the per-XCD L2, reads L3.
__device__ __forceinline__ uint4 load_coherent16(const void* p) {
    uint4 r;
    asm volatile("global_load_dwordx4 %0, %1, off sc0 sc1" : "=v"(r) : "v"(p));
    return r;
}
// Coherent 2B store: writes through past L2 so other XCDs can see it.
__device__ __forceinline__ void store_coherent2(void* p, unsigned int v) {
    asm volatile("global_store_short %0, %1, off sc0 sc1" :: "v"(p), "v"(v) : "memory");
}
__device__ __forceinline__ void wait_vm0() {
    asm volatile("s_waitcnt vmcnt(0)" ::: "memory");
}

// ---------- fp32 -> bf16 conversion (n4 = n/4 groups) ----------
__global__ void cvt_kernel(const float* __restrict__ src, bf16* __restrict__ dst, int n4) {
    int i = blockIdx.x * blockDim.x + threadIdx.x;
    if (i < n4) {
        float4 v = ((const float4*)src)[i];
        bf16x4 o;
        o[0] = (bf16)v.x; o[1] = (bf16)v.y; o[2] = (bf16)v.z; o[3] = (bf16)v.w;
        ((bf16x4*)dst)[i] = o;
    }
}

// ---------- init h0 in block-major exchange layout: hx[blk*512 + row*16 + col] ----------
__global__ void init_state(const float* __restrict__ h0, bf16* __restrict__ hx) {
    int i = blockIdx.x * blockDim.x + threadIdx.x;
    if (i < 32768) {
        int b = i >> 10, col = i & 1023;
        int blk = col >> 4, c = col & 15;
        hx[blk * 512 + b * 16 + c] = (bf16)h0[i];
    }
}

// ---------- x_proj GEMM: P[m][j] = emb[tok(m)] . W_ih[j] + bias[j], bf16 out ----------
__global__ __launch_bounds__(256) void gemm_xproj(
    const int* __restrict__ tgt, const bf16* __restrict__ emb,
    const bf16* __restrict__ wih, const float* __restrict__ bih,
    const float* __restrict__ bhh, bf16* __restrict__ P)
{
    __shared__ bf16 As[128 * 72];
    __shared__ bf16 Bs[128 * 72];
    __shared__ int tok[128];

    const int tid  = threadIdx.x;
    const int lane = tid & 63;
    const int wave = tid >> 6;
    const int wm = wave & 1, wn = wave >> 1;
    const int tileM = blockIdx.y * 128;
    const int tileN = blockIdx.x * 128;

    if (tid < 128) {
        int m = tileM + tid;
        int token = 0;
        if (m < M_TOT) {
            int t = m >> 5, b = m & 31;
            token = tgt[b * 512 + t];
            if ((unsigned)token >= 32000u) token = 0;
        }
        tok[tid] = token;
    }
    __syncthreads();

    f32x4 acc[4][4] = {};

    for (int k0 = 0; k0 < 1024; k0 += 64) {
        #pragma unroll
        for (int i = 0; i < 4; ++i) {
            int chunk = i * 256 + tid;
            int row = chunk >> 3;
            int kc  = (chunk & 7) * 8;
            const bf16* srcA = emb + (long)tok[row] * 1024 + k0 + kc;
            *(uint4*)&As[row * 72 + kc] = *(const uint4*)srcA;
            const bf16* srcB = wih + (long)(tileN + row) * 1024 + k0 + kc;
            *(uint4*)&Bs[row * 72 + kc] = *(const uint4*)srcB;
        }
        __syncthreads();
        #pragma unroll
        for (int kk = 0; kk < 64; kk += 32) {
            bf16x8 a[4], b[4];
            #pragma unroll
            for (int f = 0; f < 4; ++f) {
                a[f] = *(const bf16x8*)&As[(wm * 64 + f * 16 + (lane & 15)) * 72 + kk + (lane >> 4) * 8];
                b[f] = *(const bf16x8*)&Bs[(wn * 64 + f * 16 + (lane & 15)) * 72 + kk + (lane >> 4) * 8];
            }
            #pragma unroll
            for (int mf = 0; mf < 4; ++mf)
                #pragma unroll
                for (int nf = 0; nf < 4; ++nf)
                    acc[mf][nf] = __builtin_amdgcn_mfma_f32_16x16x32_bf16(a[mf], b[nf], acc[mf][nf], 0, 0, 0);
        }
        __syncthreads();
    }

    float bias[4];
    #pragma unroll
    for (int nf = 0; nf < 4; ++nf) {
        int j = tileN + wn * 64 + nf * 16 + (lane & 15);
        bias[nf] = bih[j] + bhh[j];
    }
    #pragma unroll
    for (int mf = 0; mf < 4; ++mf) {
        int mBase = tileM + wm * 64 + mf * 16 + ((lane >> 4) * 4);
        #pragma unroll
        for (int r = 0; r < 4; ++r) {
            int m = mBase + r;
            if (m < M_TOT) {
                #pragma unroll
                for (int nf = 0; nf < 4; ++nf) {
                    int j = tileN + wn * 64 + nf * 16 + (lane & 15);
                    P[(long)m * 4096 + j] = (bf16)(acc[mf][nf][r] + bias[nf]);
                }
            }
        }
    }
}

// ---------- persistent LSTM: 64 blocks x 16 h-cols, grid barrier w/o cache nukes ----------
__global__ __launch_bounds__(256, 1) void lstm_persist(
    const bf16* __restrict__ P, const bf16* __restrict__ whh,
    const float* __restrict__ c0, float* __restrict__ out,
    bf16* __restrict__ hxA, bf16* __restrict__ hxB,
    unsigned int* __restrict__ cnt)
{
    __shared__ bf16 hs[32 * 1024];   // h staged (XOR-swizzled)
    __shared__ float gs[4 * 32 * 17 + 4];  // gate exchange, stride 17 (pad)

    const int tid  = threadIdx.x;
    const int lane = tid & 63;
    const int wave = tid >> 6;            // = gate index (i,f,g,o)
    const int blk  = blockIdx.x;
    const int c0col = blk * 16;           // h-column base

    const int n  = lane & 15;             // MFMA col within tile
    const int kg = lane >> 4;             // k-group 0..3

    // ---- preload this wave's W_hh rows into 128 regs (reused for 511 steps) ----
    bf16x8 wreg[32];
    {
        const bf16* wrow = whh + ((long)(wave * 1024 + c0col + n)) * 1024 + kg * 8;
        #pragma unroll
        for (int i = 0; i < 32; ++i) wreg[i] = *(const bf16x8*)(wrow + i * 32);
    }

    // ---- c state in registers ----
    const int eb   = tid >> 4;            // 0..15
    const int ecol = tid & 15;
    const int hcol = c0col + ecol;
    float cReg0 = c0[eb * 1024 + hcol];
    float cReg1 = c0[(eb + 16) * 1024 + hcol];

    const int m0 = n, m1 = n + 16;

    for (int t = 0; t < 511; ++t) {
        const bf16* hin  = (t & 1) ? hxB : hxA;
        bf16*       hout = (t & 1) ? hxA : hxB;

        // ---- stage h -> LDS via coherent loads (block-major source layout) ----
        // load q (16B) covers elems [q*8, q*8+8): blk' = q>>6, r = (q&63)>>1, half = q&1
        #pragma unroll
        for (int grp = 0; grp < 2; ++grp) {
            uint4 v[8];
            #pragma unroll
            for (int j = 0; j < 8; ++j) {
                int q = (grp * 8 + j) * 256 + tid;
                v[j] = load_coherent16((const char*)hin + q * 16);
            }
            wait_vm0();
            #pragma unroll
            for (int j = 0; j < 8; ++j) {
                int q = (grp * 8 + j) * 256 + tid;
                int sb = q >> 6;            // source block 0..63
                int r  = (q & 63) >> 1;     // row 0..31
                int hf = q & 1;             // 8-elem half of the 16-col slice
                int chunk = sb * 2 + hf;    // 16B chunk index within row (0..127)
                *(uint4*)&hs[r * 1024 + ((chunk ^ (r & 7)) << 3)] = v[j];
            }
        }
        __syncthreads();

        // prefetch P[t] (normal cached loads; latency hides under K-loop)
        long pb  = (long)t * 131072 + eb * 4096 + hcol;
        long pb2 = pb + 16 * 4096;
        float p0 = (float)P[pb],        p1 = (float)P[pb + 1024];
        float p2 = (float)P[pb + 2048], p3 = (float)P[pb + 3072];
        float q0 = (float)P[pb2],        q1 = (float)P[pb2 + 1024];
        float q2 = (float)P[pb2 + 2048], q3 = (float)P[pb2 + 3072];

        f32x4 accA = {0.f, 0.f, 0.f, 0.f};
        f32x4 accB = {0.f, 0.f, 0.f, 0.f};
        #pragma unroll
        for (int i = 0; i < 32; ++i) {
            int ch = i * 4 + kg;
            bf16x8 a0 = *(const bf16x8*)&hs[m0 * 1024 + ((ch ^ (m0 & 7)) << 3)];
            bf16x8 a1 = *(const bf16x8*)&hs[m1 * 1024 + ((ch ^ (m1 & 7)) << 3)];
            accA = __builtin_amdgcn_mfma_f32_16x16x32_bf16(a0, wreg[i], accA, 0, 0, 0);
            accB = __builtin_amdgcn_mfma_f32_16x16x32_bf16(a1, wreg[i], accB, 0, 0, 0);
        }

        __syncthreads();
        #pragma unroll
        for (int r = 0; r < 4; ++r) {
            int row = (lane >> 4) * 4 + r;    // C/D: row=(lane>>4)*4+reg, col=lane&15
            gs[(wave * 32 + row) * 17 + n]        = accA[r];
            gs[(wave * 32 + row + 16) * 17 + n]   = accB[r];
        }
        __syncthreads();

        // ---- epilogue: thread owns (eb,hcol) and (eb+16,hcol) ----
        {
            float gi = gs[(0 * 32 + eb) * 17 + ecol] + p0;
            float gf = gs[(1 * 32 + eb) * 17 + ecol] + p1;
            float gg = gs[(2 * 32 + eb) * 17 + ecol] + p2;
            float go = gs[(3 * 32 + eb) * 17 + ecol] + p3;
            float ig = 1.f / (1.f + __expf(-gi));
            float fg = 1.f / (1.f + __expf(-gf));
            float g  = tanhf(gg);
            float og = 1.f / (1.f + __expf(-go));
            cReg0 = fg * cReg0 + ig * g;
            float hnew = og * tanhf(cReg0);
            out[(long)eb * RES_STRIDE + (long)t * 1024 + hcol] = hnew;
            if (t < 510) {
                bf16 hb = (bf16)hnew;
                unsigned int bits = (unsigned int)__builtin_bit_cast(unsigned short, hb);
                store_coherent2((char*)hout + (blk * 512 + tid) * 2, bits);
            } else {
                out[HT_OFF + eb * 1024 + hcol] = hnew;
                out[CT_OFF + eb * 1024 + hcol] = cReg0;
            }
        }
        {
            float gi = gs[(0 * 32 + eb + 16) * 17 + ecol] + q0;
            float gf = gs[(1 * 32 + eb + 16) * 17 + ecol] + q1;
            float gg = gs[(2 * 32 + eb + 16) * 17 + ecol] + q2;
            float go = gs[(3 * 32 + eb + 16) * 17 + ecol] + q3;
            float ig = 1.f / (1.f + __expf(-gi));
            float fg = 1.f / (1.f + __expf(-gf));
            float g  = tanhf(gg);
            float og = 1.f / (1.f + __expf(-go));
            cReg1 = fg * cReg1 + ig * g;
            float hnew = og * tanhf(cReg1);
            out[(long)(eb + 16) * RES_STRIDE + (long)t * 1024 + hcol] = hnew;
            if (t < 510) {
                bf16 hb = (bf16)hnew;
                unsigned int bits = (unsigned int)__builtin_bit_cast(unsigned short, hb);
                store_coherent2((char*)hout + (blk * 512 + 256 + tid) * 2, bits);
            } else {
                out[HT_OFF + (eb + 16) * 1024 + hcol] = hnew;
                out[CT_OFF + (eb + 16) * 1024 + hcol] = cReg1;
            }
        }

        // ---- grid barrier: relaxed atomics only (no wbl2/inv cache nukes) ----
        if (t < 510) {
            wait_vm0();          // drain this thread's sc1 h-stores
            __syncthreads();     // all threads' stores drained before signal
            if (tid == 0) {
                __hip_atomic_fetch_add(cnt, 1u, __ATOMIC_RELAXED, __HIP_MEMORY_SCOPE_AGENT);
                unsigned int target = 64u * (unsigned)(t + 1);
                while (__hip_atomic_load(cnt, __ATOMIC_RELAXED, __HIP_MEMORY_SCOPE_AGENT) < target)
                    __builtin_amdgcn_s_sleep(1);
            }
            __syncthreads();
        }
    }
}

extern "C" void kernel_launch(void* const* d_in, const int* in_sizes, int n_in,
                              void* d_out, int out_size, void* d_ws, size_t ws_size,
                              hipStream_t stream) {
    const int*   tgt  = (const int*)d_in[0];
    const float* h0   = (const float*)d_in[1];
    const float* c0   = (const float*)d_in[2];
    const float* embT = (const float*)d_in[5];
    const float* wih  = (const float*)d_in[6];
    const float* whh  = (const float*)d_in[7];
    const float* bih  = (const float*)d_in[8];
    const float* bhh  = (const float*)d_in[9];
    float* out = (float*)d_out;

    char* ws = (char*)d_ws;
    bf16*  P    = (bf16*)(ws);                 // 133,955,584 B
    bf16*  embB = (bf16*)(ws + 133955584);     // 65,536,000 B
    bf16*  wihB = (bf16*)(ws + 199491584);     //  8,388,608 B
    bf16*  whhB = (bf16*)(ws + 207880192);     //  8,388,608 B
    bf16*  hxA  = (bf16*)(ws + 216268800);     // 65,536 B (block-major h exchange)
    bf16*  hxB  = (bf16*)(ws + 216334336);     // 65,536 B
    unsigned int* cnt = (unsigned int*)(ws + 216399872);

    hipMemsetAsync(cnt, 0, 128, stream);

    cvt_kernel<<<32000, 256, 0, stream>>>(embT, embB, 32768000 / 4);
    cvt_kernel<<<4096, 256, 0, stream>>>(wih, wihB, 4194304 / 4);
    cvt_kernel<<<4096, 256, 0, stream>>>(whh, whhB, 4194304 / 4);
    init_state<<<128, 256, 0, stream>>>(h0, hxA);

    dim3 g(32, 128);
    gemm_xproj<<<g, 256, 0, stream>>>(tgt, embB, wihB, bih, bhh, P);

    lstm_persist<<<64, 256, 0, stream>>>(P, whhB, c0, out, hxA, hxB, cnt);
}

// Round 4
// 2335.371 us; speedup vs baseline: 4.0054x; 1.5215x over previous
//
#include <hip/hip_runtime.h>

// Decoder LSTM: B=32, T=511 steps, H=1024, 4H=4096, V=32000
// out = res[32][511][1024] ++ hT[32][1024] ++ cT[32][1024]  (fp32)

typedef __bf16 bf16;
typedef __bf16 bf16x4 __attribute__((ext_vector_type(4)));
typedef __bf16 bf16x8 __attribute__((ext_vector_type(8)));
typedef float f32x4 __attribute__((ext_vector_type(4)));
typedef float f32x16 __attribute__((ext_vector_type(16)));

#define M_TOT 16352        // 511*32 rows of x_proj
#define RES_STRIDE 523264  // 511*1024
#define HT_OFF 16744448    // 32*511*1024
#define CT_OFF 16777216    // HT_OFF + 32768

// Coherent (cross-XCD) ops: sc0 sc1 bypass the per-XCD L2, hit L3.
__device__ __forceinline__ uint4 load_coherent16(const void* p) {
    uint4 r;
    asm volatile("global_load_dwordx4 %0, %1, off sc0 sc1" : "=v"(r) : "v"(p));
    return r;
}
__device__ __forceinline__ unsigned int load_coherent4(const void* p) {
    unsigned int r;
    asm volatile("global_load_dword %0, %1, off sc0 sc1\n\ts_waitcnt vmcnt(0)"
                 : "=v"(r) : "v"(p) : "memory");
    return r;
}
__device__ __forceinline__ void store_coherent2(void* p, unsigned int v) {
    asm volatile("global_store_short %0, %1, off sc0 sc1" :: "v"(p), "v"(v) : "memory");
}
__device__ __forceinline__ void store_coherent4(void* p, unsigned int v) {
    asm volatile("global_store_dword %0, %1, off sc0 sc1" :: "v"(p), "v"(v) : "memory");
}
__device__ __forceinline__ void wait_vm0() {
    asm volatile("s_waitcnt vmcnt(0)" ::: "memory");
}

// ---------- fp32 -> bf16 conversion ----------
__global__ void cvt_kernel(const float* __restrict__ src, bf16* __restrict__ dst, int n4) {
    int i = blockIdx.x * blockDim.x + threadIdx.x;
    if (i < n4) {
        float4 v = ((const float4*)src)[i];
        bf16x4 o;
        o[0] = (bf16)v.x; o[1] = (bf16)v.y; o[2] = (bf16)v.z; o[3] = (bf16)v.w;
        ((bf16x4*)dst)[i] = o;
    }
}

// ---------- init h0 in block-major exchange layout: hx[blk*512 + b*16 + c] ----------
__global__ void init_state(const float* __restrict__ h0, bf16* __restrict__ hx) {
    int i = blockIdx.x * blockDim.x + threadIdx.x;
    if (i < 32768) {
        int b = i >> 10, col = i & 1023;
        int blk = col >> 4, c = col & 15;
        hx[blk * 512 + b * 16 + c] = (bf16)h0[i];
    }
}

// ---------- x_proj GEMM -> P'' block-major: P[(t*64+blk)*2048 + gate*512 + b*16 + c] ----------
__global__ __launch_bounds__(256) void gemm_xproj(
    const int* __restrict__ tgt, const bf16* __restrict__ emb,
    const bf16* __restrict__ wih, const float* __restrict__ bih,
    const float* __restrict__ bhh, bf16* __restrict__ P)
{
    __shared__ bf16 As[128 * 72];
    __shared__ bf16 Bs[128 * 72];
    __shared__ int tok[128];

    const int tid  = threadIdx.x;
    const int lane = tid & 63;
    const int wave = tid >> 6;
    const int wm = wave & 1, wn = wave >> 1;
    const int tileM = blockIdx.y * 128;
    const int tileN = blockIdx.x * 128;

    if (tid < 128) {
        int m = tileM + tid;
        int token = 0;
        if (m < M_TOT) {
            int t = m >> 5, b = m & 31;
            token = tgt[b * 512 + t];
            if ((unsigned)token >= 32000u) token = 0;
        }
        tok[tid] = token;
    }
    __syncthreads();

    f32x4 acc[4][4] = {};

    for (int k0 = 0; k0 < 1024; k0 += 64) {
        #pragma unroll
        for (int i = 0; i < 4; ++i) {
            int chunk = i * 256 + tid;
            int row = chunk >> 3;
            int kc  = (chunk & 7) * 8;
            const bf16* srcA = emb + (long)tok[row] * 1024 + k0 + kc;
            *(uint4*)&As[row * 72 + kc] = *(const uint4*)srcA;
            const bf16* srcB = wih + (long)(tileN + row) * 1024 + k0 + kc;
            *(uint4*)&Bs[row * 72 + kc] = *(const uint4*)srcB;
        }
        __syncthreads();
        #pragma unroll
        for (int kk = 0; kk < 64; kk += 32) {
            bf16x8 a[4], b[4];
            #pragma unroll
            for (int f = 0; f < 4; ++f) {
                a[f] = *(const bf16x8*)&As[(wm * 64 + f * 16 + (lane & 15)) * 72 + kk + (lane >> 4) * 8];
                b[f] = *(const bf16x8*)&Bs[(wn * 64 + f * 16 + (lane & 15)) * 72 + kk + (lane >> 4) * 8];
            }
            #pragma unroll
            for (int mf = 0; mf < 4; ++mf)
                #pragma unroll
                for (int nf = 0; nf < 4; ++nf)
                    acc[mf][nf] = __builtin_amdgcn_mfma_f32_16x16x32_bf16(a[mf], b[nf], acc[mf][nf], 0, 0, 0);
        }
        __syncthreads();
    }

    float bias[4];
    #pragma unroll
    for (int nf = 0; nf < 4; ++nf) {
        int j = tileN + wn * 64 + nf * 16 + (lane & 15);
        bias[nf] = bih[j] + bhh[j];
    }
    #pragma unroll
    for (int mf = 0; mf < 4; ++mf) {
        int mBase = tileM + wm * 64 + mf * 16 + ((lane >> 4) * 4);
        #pragma unroll
        for (int r = 0; r < 4; ++r) {
            int m = mBase + r;
            if (m < M_TOT) {
                int t = m >> 5, bb = m & 31;
                #pragma unroll
                for (int nf = 0; nf < 4; ++nf) {
                    int j = tileN + wn * 64 + nf * 16 + (lane & 15);
                    int gate = j >> 10, jc = j & 1023;
                    int pblk = jc >> 4, pc = jc & 15;
                    P[((long)(t * 64 + pblk)) * 2048 + gate * 512 + bb * 16 + pc]
                        = (bf16)(acc[mf][nf][r] + bias[nf]);
                }
            }
        }
    }
}

// ---------- persistent LSTM: 64 blocks x 512 thr (8 waves), 32x32x16 MFMA, K-split x4 ----------
__global__ __launch_bounds__(512, 1) void lstm_persist(
    const bf16* __restrict__ P, const bf16* __restrict__ whh,
    const float* __restrict__ c0, float* __restrict__ out,
    bf16* __restrict__ hxA, bf16* __restrict__ hxB,
    unsigned int* __restrict__ flags)
{
    __shared__ bf16  hs[32 * 1024];          // h staged, XOR-swizzled (64 KB)
    __shared__ float gs[4 * 64 * 33];        // K-split partials [ks][o][b], stride 33 (33.8 KB)
    __shared__ bf16  ps[2048];               // P'' block for this step (4 KB)

    const int tid  = threadIdx.x;
    const int lane = tid & 63;
    const int wave = tid >> 6;               // 0..7
    const int blk  = blockIdx.x;

    const int tp    = wave & 1;              // col-tile: gates {0,1} or {2,3}
    const int ks    = wave >> 1;             // K quarter 0..3
    const int cc    = lane & 31;             // output col within tile (0..31)
    const int khalf = lane >> 5;             // k half within MFMA (0..1)
    const int o     = tp * 32 + cc;          // flat output 0..63 within block

    // ---- preload this lane's W_hh B-fragments (16 x bf16x8 = 64 VGPRs) ----
    bf16x8 wreg[16];
    {
        const int gate = tp * 2 + (cc >> 4);
        const int wRow = gate * 1024 + blk * 16 + (cc & 15);
        const bf16* wbase = whh + (long)wRow * 1024 + ks * 256 + khalf * 8;
        #pragma unroll
        for (int i = 0; i < 16; ++i) wreg[i] = *(const bf16x8*)(wbase + i * 16);
    }

    // ---- per-thread epilogue element: (eb, ec) ----
    const int eb = tid >> 4;                 // batch row 0..31
    const int ec = tid & 15;
    const int hcol = blk * 16 + ec;
    float cReg = c0[eb * 1024 + hcol];

    const int m = lane & 31;                 // A-frag row (batch)

    for (int t = 0; t < 511; ++t) {
        const bf16* hin  = (t & 1) ? hxB : hxA;
        bf16*       hout = (t & 1) ? hxA : hxB;

        // ---- stage h (64 KB) + P'' (4 KB) -> LDS ----
        uint4 v[8];
        #pragma unroll
        for (int j = 0; j < 8; ++j) {
            int q = j * 512 + tid;           // 16B chunk id 0..4095
            v[j] = load_coherent16((const char*)hin + q * 16);
        }
        uint2 pv = *(const uint2*)((const char*)P + ((long)(t * 64 + blk)) * 4096 + tid * 8);
        wait_vm0();
        #pragma unroll
        for (int j = 0; j < 8; ++j) {
            int q = j * 512 + tid;
            int sb  = q >> 6;                // source block 0..63
            int idx = q & 63;
            int b   = idx >> 1;              // row 0..31
            int hf  = idx & 1;
            int ch  = sb * 2 + hf;           // 16B chunk within row
            *(uint4*)&hs[b * 1024 + ((ch ^ (b & 7)) << 3)] = v[j];
        }
        *(uint2*)&ps[tid * 4] = pv;
        __syncthreads();

        // ---- K-loop: 16 x mfma_32x32x16, A from LDS, B from regs ----
        f32x16 acc = {};
        #pragma unroll
        for (int i = 0; i < 16; ++i) {
            int ch = ks * 32 + i * 2 + khalf;
            bf16x8 a = *(const bf16x8*)&hs[m * 1024 + ((ch ^ (m & 7)) << 3)];
            acc = __builtin_amdgcn_mfma_f32_32x32x16_bf16(a, wreg[i], acc, 0, 0, 0);
        }

        // ---- write partials to exchange (no barrier needed before: gs != hs) ----
        #pragma unroll
        for (int r = 0; r < 16; ++r) {
            int b = (r & 3) + 8 * (r >> 2) + 4 * khalf;   // C/D row
            gs[(ks * 64 + o) * 33 + b] = acc[r];
        }
        __syncthreads();

        // ---- epilogue: one (eb, hcol) element per thread ----
        float g4[4];
        #pragma unroll
        for (int g = 0; g < 4; ++g) {
            int oo = (g >> 1) * 32 + (g & 1) * 16 + ec;
            float s = gs[(0 * 64 + oo) * 33 + eb] + gs[(1 * 64 + oo) * 33 + eb]
                    + gs[(2 * 64 + oo) * 33 + eb] + gs[(3 * 64 + oo) * 33 + eb];
            g4[g] = s + (float)ps[g * 512 + eb * 16 + ec];
        }
        float ig = 1.f / (1.f + __expf(-g4[0]));
        float fg = 1.f / (1.f + __expf(-g4[1]));
        float gg = tanhf(g4[2]);
        float og = 1.f / (1.f + __expf(-g4[3]));
        cReg = fg * cReg + ig * gg;
        float hnew = og * tanhf(cReg);

        if (t < 510) {
            bf16 hb = (bf16)hnew;
            unsigned int bits = (unsigned int)__builtin_bit_cast(unsigned short, hb);
            store_coherent2((char*)hout + (blk * 512 + tid) * 2, bits);
            wait_vm0();            // this thread's h store drained
            __syncthreads();       // all threads' h stores drained
            if (tid == 0) store_coherent4(flags + blk * 32, (unsigned)(t + 1));
            out[(long)eb * RES_STRIDE + (long)t * 1024 + hcol] = hnew;  // overlaps poll
            if (tid < 64) {        // gather-poll all 64 block flags
                const unsigned int* fp = flags + tid * 32;
                unsigned int target = (unsigned)(t + 1);
                while (true) {
                    unsigned int fv = load_coherent4(fp);
                    if (__all((int)(fv >= target))) break;
                }
            }
            __syncthreads();
        } else {
            out[(long)eb * RES_STRIDE + (long)t * 1024 + hcol] = hnew;
            out[HT_OFF + eb * 1024 + hcol] = hnew;
            out[CT_OFF + eb * 1024 + hcol] = cReg;
        }
    }
}

extern "C" void kernel_launch(void* const* d_in, const int* in_sizes, int n_in,
                              void* d_out, int out_size, void* d_ws, size_t ws_size,
                              hipStream_t stream) {
    const int*   tgt  = (const int*)d_in[0];
    const float* h0   = (const float*)d_in[1];
    const float* c0   = (const float*)d_in[2];
    const float* embT = (const float*)d_in[5];
    const float* wih  = (const float*)d_in[6];
    const float* whh  = (const float*)d_in[7];
    const float* bih  = (const float*)d_in[8];
    const float* bhh  = (const float*)d_in[9];
    float* out = (float*)d_out;

    char* ws = (char*)d_ws;
    bf16*  P    = (bf16*)(ws);                 // 133,955,584 B (block-major P'')
    bf16*  embB = (bf16*)(ws + 133955584);     // 65,536,000 B
    bf16*  wihB = (bf16*)(ws + 199491584);     //  8,388,608 B
    bf16*  whhB = (bf16*)(ws + 207880192);     //  8,388,608 B
    bf16*  hxA  = (bf16*)(ws + 216268800);     // 65,536 B (block-major h exchange)
    bf16*  hxB  = (bf16*)(ws + 216334336);     // 65,536 B
    unsigned int* flags = (unsigned int*)(ws + 216399872);  // 64 flags, 128B apart

    hipMemsetAsync(flags, 0, 64 * 32 * 4, stream);

    cvt_kernel<<<32000, 256, 0, stream>>>(embT, embB, 32768000 / 4);
    cvt_kernel<<<4096, 256, 0, stream>>>(wih, wihB, 4194304 / 4);
    cvt_kernel<<<4096, 256, 0, stream>>>(whh, whhB, 4194304 / 4);
    init_state<<<128, 256, 0, stream>>>(h0, hxA);

    dim3 g(32, 128);
    gemm_xproj<<<g, 256, 0, stream>>>(tgt, embB, wihB, bih, bhh, P);

    lstm_persist<<<64, 512, 0, stream>>>(P, whhB, c0, out, hxA, hxB, flags);
}